// Round 2
// baseline (465.410 us; speedup 1.0000x reference)
//
#include <hip/hip_runtime.h>
#include <hip/hip_bf16.h>

// RWKV6 single-token step, H=4096, NH=64, HS=64, TM=64, TD=128.
// Dtype of device buffers is ambiguous (reference is f32 but harness label says
// bf16) -> runtime-detect via ln1_w bit patterns, branch uniformly per kernel.

#define H 4096
#define HS 64
#define NH 64
#define TM 64
#define TD 128

// workspace layout (float offsets)
#define WS_XN    0
#define WS_SX    4096
#define WS_XXX   8192
#define WS_MIX   12288   // 320
#define WS_M     12608   // 5*4096 -> 33088
#define WS_RKVG  33088   // 4*4096 (r,k,v,g) -> 49472
#define WS_DD1   49472   // 128 -> 49600
#define WS_TD    49600   // 4096 -> 53696
#define WS_OG    53696   // 4096 -> 57792
#define WS_OUT   57792   // 4096 -> 61888
#define WS_FLAG  61888   // 1.0 = bf16 buffers, 0.0 = f32 buffers
#define WS_TOTAL 61892

typedef unsigned short u16;

__device__ __forceinline__ float bf2f(u16 u) {
    union { unsigned int i; float f; } c; c.i = ((unsigned int)u) << 16; return c.f;
}
__device__ __forceinline__ u16 f2bf(float f) {
    union { float f; unsigned int i; } c; c.f = f;
    unsigned int x = c.i;
    return (u16)((x + 0x7fffu + ((x >> 16) & 1u)) >> 16);  // RNE
}
__device__ __forceinline__ float ld(const void* p, size_t i, int isbf) {
    return isbf ? bf2f(((const u16*)p)[i]) : ((const float*)p)[i];
}
__device__ __forceinline__ void st(void* p, size_t i, int isbf, float v) {
    if (isbf) ((u16*)p)[i] = f2bf(v); else ((float*)p)[i] = v;
}

__global__ void k0_zero(float* ws) {
    int idx = blockIdx.x * 256 + threadIdx.x;
    for (int i = idx; i < WS_TOTAL; i += 256 * 64) ws[i] = 0.0f;
}

// dtype detect: ln1_w ~ 1.0 +- 0.1. bf16 mode: every u16 is ~1.0 as bf16.
// f32 mode: even u16 indices are random low-mantissa halves.
__global__ void kD_detect(const void* __restrict__ ln1w, float* __restrict__ ws) {
    if (threadIdx.x == 0 && blockIdx.x == 0) {
        const u16* p = (const u16*)ln1w;
        int ok = 1;
        for (int i = 0; i < 8; i++) {
            float f = bf2f(p[2 * i]);
            if (!(f > 0.5f && f < 2.0f)) ok = 0;
        }
        ws[WS_FLAG] = ok ? 1.0f : 0.0f;
    }
}

// LayerNorm + token-shift prep. 1 block x 256 threads.
__global__ void k1_ln(const void* __restrict__ x, const void* __restrict__ s1,
                      const void* __restrict__ ln1w, const void* __restrict__ ln1b,
                      const void* __restrict__ tmx, void* __restrict__ d_out,
                      float* __restrict__ ws) {
    __shared__ float red[256];
    int isbf = ws[WS_FLAG] != 0.0f;
    int tid = threadIdx.x;
    float xv[16];
    float s = 0.f, ss = 0.f;
    for (int i = 0; i < 16; i++) {
        float v = ld(x, tid * 16 + i, isbf);
        xv[i] = v; s += v; ss += v * v;
    }
    red[tid] = s; __syncthreads();
    for (int o = 128; o > 0; o >>= 1) { if (tid < o) red[tid] += red[tid + o]; __syncthreads(); }
    float mean = red[0] / (float)H;
    __syncthreads();
    red[tid] = ss; __syncthreads();
    for (int o = 128; o > 0; o >>= 1) { if (tid < o) red[tid] += red[tid + o]; __syncthreads(); }
    float var = red[0] / (float)H - mean * mean;
    float rstd = rsqrtf(var + 1e-5f);
    for (int i = 0; i < 16; i++) {
        int idx = tid * 16 + i;
        float xn = (xv[i] - mean) * rstd * ld(ln1w, idx, isbf) + ld(ln1b, idx, isbf);
        float sx = ld(s1, idx, isbf) - xn;
        ws[WS_XN + idx] = xn;
        ws[WS_SX + idx] = sx;
        ws[WS_XXX + idx] = xn + sx * ld(tmx, idx, isbf);
        st(d_out, 4096 + idx, isbf, xn);   // state1_out
    }
}

// mix partial: xxx @ W_maa1 (4096 -> 320). 64 blocks x 320 threads.
__global__ void k2_mix(const void* __restrict__ W1, float* __restrict__ ws) {
    __shared__ float xs[64];
    int isbf = ws[WS_FLAG] != 0.0f;
    int tid = threadIdx.x;
    int r0 = blockIdx.x * 64;
    if (tid < 64) xs[tid] = ws[WS_XXX + r0 + tid];
    __syncthreads();
    float acc = 0.f;
    #pragma unroll 8
    for (int i = 0; i < 64; i++) acc += xs[i] * ld(W1, (size_t)(r0 + i) * 320 + tid, isbf);
    atomicAdd(&ws[WS_MIX + tid], acc);
}

// m[s] = xn + sx*(tanh(mix[s]) @ W_maa2[s] + maa[s]). 80 blocks x 256.
__global__ void k3_m(const void* __restrict__ W2,
                     const void* __restrict__ maa_w, const void* __restrict__ maa_k,
                     const void* __restrict__ maa_v, const void* __restrict__ maa_r,
                     const void* __restrict__ maa_g, float* __restrict__ ws) {
    __shared__ float tm[64];
    int isbf = ws[WS_FLAG] != 0.0f;
    int s = blockIdx.x / 16;
    int ct = blockIdx.x % 16;
    int tid = threadIdx.x;
    if (tid < 64) tm[tid] = tanhf(ws[WS_MIX + s * 64 + tid]);
    __syncthreads();
    int h = ct * 256 + tid;
    size_t Wbase = (size_t)s * 64 * 4096;
    float acc = 0.f;
    #pragma unroll 8
    for (int t = 0; t < 64; t++) acc += tm[t] * ld(W2, Wbase + (size_t)t * 4096 + h, isbf);
    const void* maa = (s == 0) ? maa_w : (s == 1) ? maa_k : (s == 2) ? maa_v : (s == 3) ? maa_r : maa_g;
    ws[WS_M + s * 4096 + h] = ws[WS_XN + h] + ws[WS_SX + h] * (acc + ld(maa, h, isbf));
}

// big GEMV partials: r,k,v,g (4 x 4096x4096) + Wd1 (4096x128).
__global__ void k4_gemv(const void* __restrict__ Wr, const void* __restrict__ Wk,
                        const void* __restrict__ Wv, const void* __restrict__ Wg,
                        const void* __restrict__ Wd1, float* __restrict__ ws) {
    __shared__ float xs[512];
    int isbf = ws[WS_FLAG] != 0.0f;
    int b = blockIdx.x, tid = threadIdx.x;
    if (b < 512) {
        int mat = b >> 7;
        int sub = b & 127;
        int ct = sub & 3;
        int rc = sub >> 2;      // 0..31
        int r0 = rc * 128;
        const int msel[4] = {3, 1, 2, 4};   // mr, mk, mv, mg
        const void* W = (mat == 0) ? Wr : (mat == 1) ? Wk : (mat == 2) ? Wv : Wg;
        const float* in = ws + WS_M + msel[mat] * 4096;
        float* out = ws + WS_RKVG + mat * 4096;
        if (tid < 128) xs[tid] = in[r0 + tid];
        __syncthreads();
        int col = ct * 1024 + tid * 4;
        float a0 = 0.f, a1 = 0.f, a2 = 0.f, a3 = 0.f;
        if (isbf) {
            const u16* p = (const u16*)W + (size_t)r0 * 4096 + col;
            #pragma unroll 8
            for (int i = 0; i < 128; i++) {
                ushort4 w4 = *(const ushort4*)p;
                float xv = xs[i];
                a0 += xv * bf2f(w4.x); a1 += xv * bf2f(w4.y);
                a2 += xv * bf2f(w4.z); a3 += xv * bf2f(w4.w);
                p += 4096;
            }
        } else {
            const float* p = (const float*)W + (size_t)r0 * 4096 + col;
            #pragma unroll 8
            for (int i = 0; i < 128; i++) {
                float4 w4 = *(const float4*)p;
                float xv = xs[i];
                a0 += xv * w4.x; a1 += xv * w4.y;
                a2 += xv * w4.z; a3 += xv * w4.w;
                p += 4096;
            }
        }
        atomicAdd(&out[col], a0);     atomicAdd(&out[col + 1], a1);
        atomicAdd(&out[col + 2], a2); atomicAdd(&out[col + 3], a3);
    } else {
        int rc = b - 512;       // 0..7
        int r0 = rc * 512;
        xs[tid] = ws[WS_M + r0 + tid];              // mw = m[0]
        xs[tid + 256] = ws[WS_M + r0 + 256 + tid];
        __syncthreads();
        if (tid < 128) {
            float acc = 0.f;
            #pragma unroll 8
            for (int i = 0; i < 512; i++) acc += xs[i] * ld(Wd1, (size_t)(r0 + i) * 128 + tid, isbf);
            atomicAdd(&ws[WS_DD1 + tid], acc);
        }
    }
}

// dd = tanh(dd1) @ Wd2; td = exp(-exp(time_decay + dd)). 16 blocks x 256.
__global__ void k5_dd(const void* __restrict__ Wd2, const void* __restrict__ time_decay,
                      float* __restrict__ ws) {
    __shared__ float t[128];
    int isbf = ws[WS_FLAG] != 0.0f;
    int tid = threadIdx.x;
    if (tid < 128) t[tid] = tanhf(ws[WS_DD1 + tid]);
    __syncthreads();
    int h = blockIdx.x * 256 + tid;
    float acc = 0.f;
    #pragma unroll 8
    for (int j = 0; j < 128; j++) acc += t[j] * ld(Wd2, (size_t)j * 4096 + h, isbf);
    ws[WS_TD + h] = expf(-expf(ld(time_decay, h, isbf) + acc));
}

// per-head attention + state update + InstanceNorm + gate. 64 blocks x 64 threads.
__global__ void k6_attn(const void* __restrict__ state2, const void* __restrict__ faaaa,
                        const void* __restrict__ lnxw, const void* __restrict__ lnxb,
                        void* __restrict__ d_out, float* __restrict__ ws) {
    __shared__ float kk[64], rr[64], ff[64], tt[64];
    int isbf = ws[WS_FLAG] != 0.0f;
    int h = blockIdx.x, j = threadIdx.x;
    int base = h * 64;
    rr[j] = ws[WS_RKVG + 0 * 4096 + base + j];
    kk[j] = ws[WS_RKVG + 1 * 4096 + base + j];
    ff[j] = ld(faaaa, base + j, isbf);
    tt[j] = ws[WS_TD + base + j];
    __syncthreads();
    float vj = ws[WS_RKVG + 2 * 4096 + base + j];
    float outj = 0.f;
    size_t s2base = (size_t)h * 4096;
    for (int i = 0; i < 64; i++) {
        float s2 = ld(state2, s2base + i * 64 + j, isbf);
        float kv = kk[i] * vj;
        outj += rr[i] * (kv * ff[i] + s2);
        st(d_out, (size_t)8192 + s2base + i * 64 + j, isbf, kv + s2 * tt[i]);  // state2_out
    }
    // wave-wide (64-lane) mean/var
    float s = outj, ss = outj * outj;
    for (int o = 1; o < 64; o <<= 1) { s += __shfl_xor(s, o, 64); ss += __shfl_xor(ss, o, 64); }
    float mean = s * (1.0f / 64.0f);
    float var = ss * (1.0f / 64.0f) - mean * mean;
    float normed = (outj - mean) * rsqrtf(var + 1e-5f);
    float o = normed * ld(lnxw, base + j, isbf) + ld(lnxb, base + j, isbf);
    float g = ws[WS_RKVG + 3 * 4096 + base + j];
    ws[WS_OG + base + j] = o * g / (1.0f + expf(-g));
}

// Wo GEMV partials: 128 blocks (4 col tiles x 32 row chunks of 128 rows) x 256.
__global__ void k7_wo(const void* __restrict__ Wo, float* __restrict__ ws) {
    __shared__ float xs[128];
    int isbf = ws[WS_FLAG] != 0.0f;
    int b = blockIdx.x, tid = threadIdx.x;
    int ct = b & 3;
    int rc = b >> 2;        // 0..31
    int r0 = rc * 128;
    if (tid < 128) xs[tid] = ws[WS_OG + r0 + tid];
    __syncthreads();
    int col = ct * 1024 + tid * 4;
    float a0 = 0.f, a1 = 0.f, a2 = 0.f, a3 = 0.f;
    if (isbf) {
        const u16* p = (const u16*)Wo + (size_t)r0 * 4096 + col;
        #pragma unroll 8
        for (int i = 0; i < 128; i++) {
            ushort4 w4 = *(const ushort4*)p;
            float xv = xs[i];
            a0 += xv * bf2f(w4.x); a1 += xv * bf2f(w4.y);
            a2 += xv * bf2f(w4.z); a3 += xv * bf2f(w4.w);
            p += 4096;
        }
    } else {
        const float* p = (const float*)Wo + (size_t)r0 * 4096 + col;
        #pragma unroll 8
        for (int i = 0; i < 128; i++) {
            float4 w4 = *(const float4*)p;
            float xv = xs[i];
            a0 += xv * w4.x; a1 += xv * w4.y;
            a2 += xv * w4.z; a3 += xv * w4.w;
            p += 4096;
        }
    }
    float* out = ws + WS_OUT;
    atomicAdd(&out[col], a0);     atomicAdd(&out[col + 1], a1);
    atomicAdd(&out[col + 2], a2); atomicAdd(&out[col + 3], a3);
}

// residual add + store. 16 blocks x 256.
__global__ void k8_final(const void* __restrict__ x, void* __restrict__ d_out,
                         const float* __restrict__ ws) {
    int isbf = ws[WS_FLAG] != 0.0f;
    int idx = blockIdx.x * 256 + threadIdx.x;
    st(d_out, idx, isbf, ld(x, idx, isbf) + ws[WS_OUT + idx]);
}

extern "C" void kernel_launch(void* const* d_in, const int* in_sizes, int n_in,
                              void* d_out, int out_size, void* d_ws, size_t ws_size,
                              hipStream_t stream) {
    const void* x     = d_in[0];
    const void* s1    = d_in[1];
    const void* s2    = d_in[2];
    const void* ln1w  = d_in[3];
    const void* ln1b  = d_in[4];
    const void* tmx   = d_in[5];
    const void* tmw   = d_in[6];
    const void* tmk   = d_in[7];
    const void* tmv   = d_in[8];
    const void* tmr   = d_in[9];
    const void* tmg   = d_in[10];
    const void* W1    = d_in[11];
    const void* W2    = d_in[12];
    const void* tdec  = d_in[13];
    const void* Wd1   = d_in[14];
    const void* Wd2   = d_in[15];
    const void* faaaa = d_in[16];
    const void* Wr    = d_in[17];
    const void* Wk    = d_in[18];
    const void* Wv    = d_in[19];
    const void* Wg    = d_in[20];
    const void* Wo    = d_in[21];
    const void* lnxw  = d_in[22];
    const void* lnxb  = d_in[23];

    float* ws = (float*)d_ws;

    hipLaunchKernelGGL(k0_zero, dim3(64), dim3(256), 0, stream, ws);
    hipLaunchKernelGGL(kD_detect, dim3(1), dim3(64), 0, stream, ln1w, ws);
    hipLaunchKernelGGL(k1_ln, dim3(1), dim3(256), 0, stream, x, s1, ln1w, ln1b, tmx, d_out, ws);
    hipLaunchKernelGGL(k2_mix, dim3(64), dim3(320), 0, stream, W1, ws);
    hipLaunchKernelGGL(k3_m, dim3(80), dim3(256), 0, stream, W2, tmw, tmk, tmv, tmr, tmg, ws);
    hipLaunchKernelGGL(k4_gemv, dim3(520), dim3(256), 0, stream, Wr, Wk, Wv, Wg, Wd1, ws);
    hipLaunchKernelGGL(k5_dd, dim3(16), dim3(256), 0, stream, Wd2, tdec, ws);
    hipLaunchKernelGGL(k6_attn, dim3(64), dim3(64), 0, stream, s2, faaaa, lnxw, lnxb, d_out, ws);
    hipLaunchKernelGGL(k7_wo, dim3(128), dim3(256), 0, stream, Wo, ws);
    hipLaunchKernelGGL(k8_final, dim3(16), dim3(256), 0, stream, x, d_out, ws);
}